// Round 5
// baseline (964.249 us; speedup 1.0000x reference)
//
#include <hip/hip_runtime.h>

// ---------------------------------------------------------------------------
// RhythmSNN forward, de-sequentialized:
//   0. transpose masks -> maskT[t][h] (scratch inside d_out, dead until gemm3)
//   1. split dec_w (fp32) -> K-interleaved [hi|lo] bf16 W2[32000][1024]   (ws)
//   2. state1 = gather(enc_w, raw) @ fc1          (fp32 tiled GEMM, fused gather)
//   3. scan1 -> s1 (fp32 {0,1})                   (coalesced, unroll 8)
//   4. state2 = s1 @ fc2                          (fp32 tiled GEMM)
//   5. scan2 -> s2 duplicated along K (bf16)      A2[4096][1024]
//   6. out = A2 @ W2^T + dec_b                    (MFMA bf16, ring-4 depth-3
//                                                  counted-vmcnt, 256x256, BK=32)
// ---------------------------------------------------------------------------

typedef __attribute__((ext_vector_type(8))) short short8;
typedef __attribute__((ext_vector_type(4))) float f32x4;
typedef __attribute__((ext_vector_type(8))) unsigned short us8;

#define WAITVM(N) asm volatile("s_waitcnt vmcnt(" #N ")" ::: "memory")

__device__ __forceinline__ unsigned short f2bf(float f) {
    unsigned int u = __float_as_uint(f);
    unsigned int r = (u + 0x7FFFu + ((u >> 16) & 1u)) >> 16;   // RNE
    return (unsigned short)r;
}

// ---------------- 0. mask transpose: maskT[t*512+h] = mask[h*3136+t] -------
__global__ __launch_bounds__(256) void maskT_kernel(
    const float* __restrict__ m1, const float* __restrict__ m2,
    float* __restrict__ t1, float* __restrict__ t2)
{
    int i = blockIdx.x * 256 + threadIdx.x;   // 65536 total
    int h = i >> 7, t = i & 127;              // coalesced reads along t
    t1[t * 512 + h] = m1[(size_t)h * 3136 + t];
    t2[t * 512 + h] = m2[(size_t)h * 3136 + t];
}

// ---------------- 1. split dec_w -> K-interleaved hi/lo bf16 ---------------
// flat fp32 id 4i covers (n, k..k+3); output u16 index = 2*(n*512+k) = 8i.
__global__ __launch_bounds__(256) void split_kernel(
    const float* __restrict__ w, unsigned short* __restrict__ w2, int n4)
{
    int i = blockIdx.x * 256 + threadIdx.x;
    if (i >= n4) return;
    float4 v = ((const float4*)w)[i];
    float vv[4] = {v.x, v.y, v.z, v.w};
    us8 o;
    #pragma unroll
    for (int c = 0; c < 4; ++c) {
        unsigned short hb = f2bf(vv[c]);
        float hf = __uint_as_float(((unsigned int)hb) << 16);
        o[2 * c]     = hb;
        o[2 * c + 1] = f2bf(vv[c] - hf);   // exact residual, then RNE
    }
    ((us8*)w2)[i] = o;
}

// ---------------- 2./4. fp32 tiled GEMM (64x64 tile, 4x4 microtile) --------
// C[M,N] = A[M,K] @ B[K,N];  if gidx != null, A row i = gtable[gidx[i]*K ...]
__global__ __launch_bounds__(256) void gemm_f32_kernel(
    const float* __restrict__ A, const float* __restrict__ B,
    float* __restrict__ C, int M, int N, int K,
    const int* __restrict__ gidx, const float* __restrict__ gtable)
{
    __shared__ float As[16][64];
    __shared__ float Bs[16][64];
    int tid = threadIdx.x;
    int bn0 = blockIdx.x * 64, bm0 = blockIdx.y * 64;

    int lrowA = tid >> 2;
    int lkA   = (tid & 3) * 4;
    int lkB   = tid >> 4;
    int lnB   = (tid & 15) * 4;
    int ty = tid >> 4, tx = tid & 15;

    const float* Abase;
    size_t aoff;
    int grow = bm0 + lrowA;
    if (gidx) { Abase = gtable; aoff = (size_t)gidx[grow] * K; }
    else      { Abase = A;      aoff = (size_t)grow * K; }

    float acc[4][4];
    #pragma unroll
    for (int i = 0; i < 4; ++i)
        #pragma unroll
        for (int j = 0; j < 4; ++j) acc[i][j] = 0.f;

    for (int k0 = 0; k0 < K; k0 += 16) {
        float4 av = *(const float4*)(Abase + aoff + k0 + lkA);
        As[lkA + 0][lrowA] = av.x;
        As[lkA + 1][lrowA] = av.y;
        As[lkA + 2][lrowA] = av.z;
        As[lkA + 3][lrowA] = av.w;
        float4 bv = *(const float4*)(B + (size_t)(k0 + lkB) * N + bn0 + lnB);
        *(float4*)&Bs[lkB][lnB] = bv;
        __syncthreads();
        #pragma unroll
        for (int kk = 0; kk < 16; ++kk) {
            float4 aq = *(float4*)&As[kk][ty * 4];
            float4 bq = *(float4*)&Bs[kk][tx * 4];
            float aa[4] = {aq.x, aq.y, aq.z, aq.w};
            float bb[4] = {bq.x, bq.y, bq.z, bq.w};
            #pragma unroll
            for (int i = 0; i < 4; ++i)
                #pragma unroll
                for (int j = 0; j < 4; ++j) acc[i][j] += aa[i] * bb[j];
        }
        __syncthreads();
    }
    #pragma unroll
    for (int i = 0; i < 4; ++i) {
        float4 v = {acc[i][0], acc[i][1], acc[i][2], acc[i][3]};
        *(float4*)(C + (size_t)(bm0 + ty * 4 + i) * N + bn0 + tx * 4) = v;
    }
}

// ---------------- 3./5. membrane scan (coalesced maskT, unroll 8) ----------
template <int DUP>
__global__ __launch_bounds__(64) void scan_kernel(
    const float* __restrict__ state, const float* __restrict__ maskT,
    float* __restrict__ outF, unsigned int* __restrict__ outU)
{
    int tid = blockIdx.x * 64 + threadIdx.x;   // < 32*512
    int b = tid >> 9, h = tid & 511;
    float mem = 0.f;
    #pragma unroll 8
    for (int t = 0; t < 128; ++t) {
        size_t ridx = (size_t)(t * 32 + b) * 512 + h;
        float st = state[ridx];
        float m  = maskT[t * 512 + h];
        float nm = (mem > 0.6f) ? st : mem * 0.6f + st;   // reset uses OLD mem
        mem = (m == 0.0f) ? mem : nm;
        float spf = (mem > 0.6f) ? m : 0.0f;              // heaviside * mask
        if (DUP) outU[ridx] = f2bf(spf) * 0x10001u;       // dup along K
        else     outF[ridx] = spf;
    }
}

// ---------------- 6. decode GEMM: 256x256 tile, ring-4 depth-3 vmcnt -------
// C[4096, 32000] = A[4096,1024] @ W[32000,1024]^T + bias
// 512 thr = 8 waves (2x4). BK=32. LDS ring of 4 slots x (A 16KB + B 16KB).
// Stage K-tile t+3 while computing t; WAITVM(8) + s_barrier per step (counted,
// never 0 until the tail). Slot written at t is (t-1)&3, last read at t-1
// strictly before the barrier we just passed -> race-free.
// Chunk swizzle c ^= (row + (row>>2)) & 3 (16B chunks, 4/row): per-16-lane
// read quarter the chunk-group histogram is exactly 2 per group (2-way = free,
// m136); unswizzled is 8-way. Applied on gload SOURCE and ds READ, LDS linear
// (rule #21).
__global__ __launch_bounds__(512, 2) void gemm3_kernel(
    const unsigned short* __restrict__ A,
    const unsigned short* __restrict__ W,
    const float* __restrict__ bias, float* __restrict__ C)
{
    constexpr int K = 1024, NTOK = 32000;
    __shared__ char lds[131072];

    int tid  = threadIdx.x;
    int lane = tid & 63;
    int wid  = __builtin_amdgcn_readfirstlane(tid >> 6);

    // XCD bijective swizzle: 2000 blocks, 2000/8 = 250; mt fast within an XCD
    // -> ~16 co-resident blocks share one W panel via L2.
    int bid = blockIdx.x;
    int swz = (bid & 7) * 250 + (bid >> 3);
    int mt = swz & 15;          // 16 M-tiles
    int nt = swz >> 4;          // 125 N-tiles
    int m0 = mt * 256, n0 = nt * 256;

    int wm = wid >> 2, wn = wid & 3;   // wave owns rows wm*128+, cols wn*64+

    // Per-thread stage sources: chunk q = i*512+tid of a slot (A: q<1024, B rest)
    const unsigned short* srcB[4];
    int dstOff[4];
    #pragma unroll
    for (int i = 0; i < 4; ++i) {
        int q   = i * 512 + tid;
        int isB = q >> 10;
        int qq  = q & 1023;
        int row = qq >> 2;                      // 0..255
        int cp  = qq & 3;                       // LDS chunk column
        int c   = cp ^ ((row + (row >> 2)) & 3);  // source chunk column
        srcB[i] = (isB ? W + (size_t)(n0 + row) * K
                       : A + (size_t)(m0 + row) * K) + c * 8;
        dstOff[i] = (i * 512 + wid * 64) * 16;  // wave-uniform; HW adds lane*16
    }

    // ds_read byte offsets within a slot (A at 0, B at 16384; row stride 64B)
    int r = lane & 15, co = lane >> 4;
    int aOff[8], bOff[4];
    #pragma unroll
    for (int mf = 0; mf < 8; ++mf) {
        int row = wm * 128 + mf * 16 + r;
        aOff[mf] = row * 64 + ((co ^ ((row + (row >> 2)) & 3)) * 16);
    }
    #pragma unroll
    for (int nf = 0; nf < 4; ++nf) {
        int row = wn * 64 + nf * 16 + r;
        bOff[nf] = 16384 + row * 64 + ((co ^ ((row + (row >> 2)) & 3)) * 16);
    }

    f32x4 acc[8][4];
    #pragma unroll
    for (int i = 0; i < 8; ++i)
        #pragma unroll
        for (int j = 0; j < 4; ++j) acc[i][j] = (f32x4){0.f, 0.f, 0.f, 0.f};

    auto STAGE = [&](int slot, int kt) {
        #pragma unroll
        for (int i = 0; i < 4; ++i) {
            __builtin_amdgcn_global_load_lds(
                (const __attribute__((address_space(1))) unsigned int*)(srcB[i] + kt * 32),
                (__attribute__((address_space(3))) unsigned int*)(lds + (slot << 15) + dstOff[i]),
                16, 0, 0);
        }
    };
    auto COMPUTE = [&](int t) {
        const char* base = lds + ((t & 3) << 15);
        short8 fa[8], fb[4];
        #pragma unroll
        for (int mf = 0; mf < 8; ++mf) fa[mf] = *(const short8*)(base + aOff[mf]);
        #pragma unroll
        for (int nf = 0; nf < 4; ++nf) fb[nf] = *(const short8*)(base + bOff[nf]);
        __builtin_amdgcn_s_setprio(1);
        #pragma unroll
        for (int mf = 0; mf < 8; ++mf)
            #pragma unroll
            for (int nf = 0; nf < 4; ++nf)
                acc[mf][nf] = __builtin_amdgcn_mfma_f32_16x16x32_bf16(
                    fa[mf], fb[nf], acc[mf][nf], 0, 0, 0);
        __builtin_amdgcn_s_setprio(0);
    };

    // Prologue: kt 0,1,2 -> slots 0,1,2; wait kt0 (oldest 4 of 12 outstanding)
    STAGE(0, 0);
    STAGE(1, 1);
    STAGE(2, 2);
    WAITVM(8);
    __builtin_amdgcn_s_barrier();
    __builtin_amdgcn_sched_barrier(0);

    // Steady state: 29 iters, stage kt=t+3, keep 8 loads in flight at barrier
    #pragma unroll 4
    for (int t = 0; t < 29; ++t) {
        STAGE((t + 3) & 3, t + 3);
        COMPUTE(t);
        WAITVM(8);                    // kt=t+1 landed; t+2, t+3 in flight
        __builtin_amdgcn_s_barrier();
        __builtin_amdgcn_sched_barrier(0);
    }
    // Tail: kt 29,30,31 already staged
    COMPUTE(29);
    WAITVM(4);                        // kt=30 landed
    __builtin_amdgcn_s_barrier();
    __builtin_amdgcn_sched_barrier(0);
    COMPUTE(30);
    WAITVM(0);                        // kt=31 landed
    __builtin_amdgcn_s_barrier();
    __builtin_amdgcn_sched_barrier(0);
    COMPUTE(31);

    // Epilogue: C/D layout col = lane&15, row = (lane>>4)*4 + reg  [m89]
    int lr = lane >> 4, lc = lane & 15;
    #pragma unroll
    for (int nf = 0; nf < 4; ++nf) {
        int gc = n0 + wn * 64 + nf * 16 + lc;
        float bv = bias[gc];
        #pragma unroll
        for (int mf = 0; mf < 8; ++mf) {
            int gr = m0 + wm * 128 + mf * 16 + lr * 4;
            f32x4 v = acc[mf][nf];
            #pragma unroll
            for (int j = 0; j < 4; ++j)
                C[(size_t)(gr + j) * NTOK + gc] = v[j] + bv;
        }
    }
}

// ---------------------------------------------------------------------------
extern "C" void kernel_launch(void* const* d_in, const int* in_sizes, int n_in,
                              void* d_out, int out_size, void* d_ws, size_t ws_size,
                              hipStream_t stream)
{
    const int*   raw   = (const int*)  d_in[0];
    const float* enc_w = (const float*)d_in[1];
    const float* fc1   = (const float*)d_in[2];
    const float* fc2   = (const float*)d_in[3];
    const float* dec_w = (const float*)d_in[4];
    const float* dec_b = (const float*)d_in[5];
    const float* mask1 = (const float*)d_in[6];
    const float* mask2 = (const float*)d_in[7];
    float* out = (float*)d_out;

    const int H1 = 512, H2 = 512, NINP = 256, NTOK = 32000;
    const int M = 128 * 32;   // T*B = 4096

    // ws layout (~80MB):
    //   [0,8MB)   st  : state1, then state2 (fp32 [4096][512])
    //   [8,16MB)  spF : s1 fp32; later A2 (s2 dup bf16 [4096][1024])
    //   [16MB,..) W2  : K-interleaved hi/lo bf16 [32000][1024] (65.5MB)
    // maskT scratch lives in d_out (524MB, fully overwritten by gemm3).
    char* ws = (char*)d_ws;
    float*          st  = (float*)ws;
    float*          spF = (float*)(ws + (size_t)(8u << 20));
    unsigned int*   a2u = (unsigned int*)(ws + (size_t)(8u << 20));
    unsigned short* A2  = (unsigned short*)(ws + (size_t)(8u << 20));
    unsigned short* W2  = (unsigned short*)(ws + (size_t)(16u << 20));
    float* mT1 = (float*)d_out;            // 128*512 f32 = 256KB
    float* mT2 = (float*)d_out + 65536;    // next 256KB

    // 0. transpose masks into d_out scratch
    maskT_kernel<<<256, 256, 0, stream>>>(mask1, mask2, mT1, mT2);

    // 1. split dec_w -> W2
    int n4 = NTOK * H2 / 4;
    split_kernel<<<(n4 + 255) / 256, 256, 0, stream>>>(dec_w, W2, n4);

    // 2. state1 = gather(enc_w, raw) @ fc1
    gemm_f32_kernel<<<dim3(H1 / 64, M / 64), 256, 0, stream>>>(
        nullptr, fc1, st, M, H1, NINP, raw, enc_w);

    // 3. scan1 -> s1 (fp32)
    scan_kernel<0><<<256, 64, 0, stream>>>(st, mT1, spF, nullptr);

    // 4. state2 = s1 @ fc2
    gemm_f32_kernel<<<dim3(H2 / 64, M / 64), 256, 0, stream>>>(
        spF, fc2, st, M, H2, H1, nullptr, nullptr);

    // 5. scan2 -> s2 duplicated bf16 (overwrites dead s1 region)
    scan_kernel<1><<<256, 64, 0, stream>>>(st, mT2, nullptr, a2u);

    // 6. out = A2 @ W2^T + dec_b (overwrites maskT scratch)
    gemm3_kernel<<<(M / 256) * (NTOK / 256), 512, 0, stream>>>(A2, W2, dec_b, out);

    (void)in_sizes; (void)n_in; (void)out_size; (void)ws_size;
}

// Round 6
// 932.531 us; speedup vs baseline: 1.0340x; 1.0340x over previous
//
#include <hip/hip_runtime.h>

// ---------------------------------------------------------------------------
// RhythmSNN forward, de-sequentialized:
//   0. transpose masks -> maskT[t][h] (scratch inside d_out, dead until gemm3)
//   1. split dec_w (fp32) -> K-interleaved [hi|lo] bf16 W2[32000][1024]   (ws)
//   2. state1 = gather(enc_w, raw) @ fc1          (fp32 tiled GEMM, fused gather)
//   3. scan1 -> s1 (fp32 {0,1})
//   4. state2 = s1 @ fc2                          (fp32 tiled GEMM)
//   5. scan2 -> s2 duplicated along K (bf16)      A2[4096][1024]
//   6. out = A2 @ W2^T + dec_b   (MFMA bf16, ring-4 counted-vmcnt + 2-phase
//                                 interleave, conflict-free paired-row LDS)
// ---------------------------------------------------------------------------

typedef __attribute__((ext_vector_type(8))) short short8;
typedef __attribute__((ext_vector_type(4))) float f32x4;
typedef __attribute__((ext_vector_type(8))) unsigned short us8;

#define WAITVM(N) asm volatile("s_waitcnt vmcnt(" #N ")" ::: "memory")
#define LGKM0()   asm volatile("s_waitcnt lgkmcnt(0)" ::: "memory")

__device__ __forceinline__ unsigned short f2bf(float f) {
    unsigned int u = __float_as_uint(f);
    unsigned int r = (u + 0x7FFFu + ((u >> 16) & 1u)) >> 16;   // RNE
    return (unsigned short)r;
}

// ---------------- 0. mask transpose: maskT[t*512+h] = mask[h*3136+t] -------
__global__ __launch_bounds__(256) void maskT_kernel(
    const float* __restrict__ m1, const float* __restrict__ m2,
    float* __restrict__ t1, float* __restrict__ t2)
{
    int i = blockIdx.x * 256 + threadIdx.x;   // 65536 total
    int h = i >> 7, t = i & 127;              // coalesced reads along t
    t1[t * 512 + h] = m1[(size_t)h * 3136 + t];
    t2[t * 512 + h] = m2[(size_t)h * 3136 + t];
}

// ---------------- 1. split dec_w -> K-interleaved hi/lo bf16 ---------------
__global__ __launch_bounds__(256) void split_kernel(
    const float* __restrict__ w, unsigned short* __restrict__ w2, int n4)
{
    int i = blockIdx.x * 256 + threadIdx.x;
    if (i >= n4) return;
    float4 v = ((const float4*)w)[i];
    float vv[4] = {v.x, v.y, v.z, v.w};
    us8 o;
    #pragma unroll
    for (int c = 0; c < 4; ++c) {
        unsigned short hb = f2bf(vv[c]);
        float hf = __uint_as_float(((unsigned int)hb) << 16);
        o[2 * c]     = hb;
        o[2 * c + 1] = f2bf(vv[c] - hf);   // exact residual, then RNE
    }
    ((us8*)w2)[i] = o;
}

// ---------------- 2./4. fp32 tiled GEMM (64x64 tile, 4x4 microtile) --------
// Unchanged (k-ascending order => bit-identical fp32; protects absmax 0.0).
__global__ __launch_bounds__(256) void gemm_f32_kernel(
    const float* __restrict__ A, const float* __restrict__ B,
    float* __restrict__ C, int M, int N, int K,
    const int* __restrict__ gidx, const float* __restrict__ gtable)
{
    __shared__ float As[16][64];
    __shared__ float Bs[16][64];
    int tid = threadIdx.x;
    int bn0 = blockIdx.x * 64, bm0 = blockIdx.y * 64;

    int lrowA = tid >> 2;
    int lkA   = (tid & 3) * 4;
    int lkB   = tid >> 4;
    int lnB   = (tid & 15) * 4;
    int ty = tid >> 4, tx = tid & 15;

    const float* Abase;
    size_t aoff;
    int grow = bm0 + lrowA;
    if (gidx) { Abase = gtable; aoff = (size_t)gidx[grow] * K; }
    else      { Abase = A;      aoff = (size_t)grow * K; }

    float acc[4][4];
    #pragma unroll
    for (int i = 0; i < 4; ++i)
        #pragma unroll
        for (int j = 0; j < 4; ++j) acc[i][j] = 0.f;

    for (int k0 = 0; k0 < K; k0 += 16) {
        float4 av = *(const float4*)(Abase + aoff + k0 + lkA);
        As[lkA + 0][lrowA] = av.x;
        As[lkA + 1][lrowA] = av.y;
        As[lkA + 2][lrowA] = av.z;
        As[lkA + 3][lrowA] = av.w;
        float4 bv = *(const float4*)(B + (size_t)(k0 + lkB) * N + bn0 + lnB);
        *(float4*)&Bs[lkB][lnB] = bv;
        __syncthreads();
        #pragma unroll
        for (int kk = 0; kk < 16; ++kk) {
            float4 aq = *(float4*)&As[kk][ty * 4];
            float4 bq = *(float4*)&Bs[kk][tx * 4];
            float aa[4] = {aq.x, aq.y, aq.z, aq.w};
            float bb[4] = {bq.x, bq.y, bq.z, bq.w};
            #pragma unroll
            for (int i = 0; i < 4; ++i)
                #pragma unroll
                for (int j = 0; j < 4; ++j) acc[i][j] += aa[i] * bb[j];
        }
        __syncthreads();
    }
    #pragma unroll
    for (int i = 0; i < 4; ++i) {
        float4 v = {acc[i][0], acc[i][1], acc[i][2], acc[i][3]};
        *(float4*)(C + (size_t)(bm0 + ty * 4 + i) * N + bn0 + tx * 4) = v;
    }
}

// ---------------- 3./5. membrane scan (batched loads, coalesced) -----------
template <int DUP>
__global__ __launch_bounds__(64) void scan_kernel(
    const float* __restrict__ state, const float* __restrict__ maskT,
    float* __restrict__ outF, unsigned int* __restrict__ outU)
{
    int tid = blockIdx.x * 64 + threadIdx.x;   // < 32*512
    int b = tid >> 9, h = tid & 511;
    float mem = 0.f;
    for (int t0 = 0; t0 < 128; t0 += 8) {
        float st8[8], m8[8];
        #pragma unroll
        for (int u = 0; u < 8; ++u) {
            st8[u] = state[(size_t)((t0 + u) * 32 + b) * 512 + h];
            m8[u]  = maskT[(t0 + u) * 512 + h];
        }
        #pragma unroll
        for (int u = 0; u < 8; ++u) {
            float nm = (mem > 0.6f) ? st8[u] : mem * 0.6f + st8[u];  // old-mem reset
            mem = (m8[u] == 0.0f) ? mem : nm;
            float spf = (mem > 0.6f) ? m8[u] : 0.0f;                 // heaviside*mask
            size_t ridx = (size_t)((t0 + u) * 32 + b) * 512 + h;
            if (DUP) outU[ridx] = f2bf(spf) * 0x10001u;              // dup along K
            else     outF[ridx] = spf;
        }
    }
}

// ---------------- 6. decode GEMM: 256x256, ring-4 + 2-phase interleave -----
// C[4096, 32000] = A[4096,1024] @ W[32000,1024]^T + bias
// 512 thr = 8 waves (2M x 4N). BK=32. Ring of 4 slots x 32KB (A 16K + B 16K).
// Paired-row LDS: LDS row j (128B, 8 chunks of 16B) holds tile rows {2j,2j+1},
// chunk swizzle c ^= (j&7). Per 16-lane ds_read_b128 group every chunk-group
// is hit exactly 2x (2-way = free, m136) -- isomorphic to the layout that
// measured ZERO conflicts in round 2. Swizzle on gload SOURCE + ds READ,
// LDS linear (rule #21).
// Pipeline: stage kt=t+3 (2 gloads per phase); per K-step 2 phases of
// {reads -> barrier -> lgkmcnt(0) -> setprio1 16 MFMA setprio0 -> barrier};
// WAITVM(8) once per step (counted, never 0 until tail). Ledger: at end of
// step t the last 8 outstanding loads are kt+2,kt+3 => kt+1 landed for t+1.
__global__ __launch_bounds__(512, 2) void gemm3_kernel(
    const unsigned short* __restrict__ A,
    const unsigned short* __restrict__ W,
    const float* __restrict__ bias, float* __restrict__ C)
{
    constexpr int K = 1024, NTOK = 32000;
    __shared__ char lds[131072];

    int tid  = threadIdx.x;
    int lane = tid & 63;
    int wid  = __builtin_amdgcn_readfirstlane(tid >> 6);

    // XCD bijective swizzle: 2000 blocks, 250/XCD; mt fast -> W-panel L2 reuse
    int bid = blockIdx.x;
    int swz = (bid & 7) * 250 + (bid >> 3);
    int mt = swz & 15;          // 16 M-tiles
    int nt = swz >> 4;          // 125 N-tiles
    int m0 = mt * 256, n0 = nt * 256;

    int wm = wid >> 2, wn = wid & 3;   // wave rows wm*128+, cols wn*64+

    // Stage sources: chunk q = i*512+tid of a slot (A: q<1024, B: rest).
    // LDS chunk (j, cp) <- global (row = 2j + (c>>2), koct = c&3), c = cp^(j&7)
    const unsigned short* srcB[4];
    int dstOff[4];
    #pragma unroll
    for (int i = 0; i < 4; ++i) {
        int q   = i * 512 + tid;
        int isB = q >> 10;
        int qq  = q & 1023;
        int j   = qq >> 3;
        int cp  = qq & 7;
        int c   = cp ^ (j & 7);
        int row = 2 * j + (c >> 2);
        srcB[i] = (isB ? W + (size_t)(n0 + row) * K
                       : A + (size_t)(m0 + row) * K) + (c & 3) * 8;
        dstOff[i] = (i * 512 + wid * 64) * 16;  // wave-uniform; HW adds lane*16
    }

    // ds_read byte offsets within a slot (A at 0, B at 16384)
    int r = lane & 15, co = lane >> 4;
    int aOff[8], bOff[4];
    #pragma unroll
    for (int mf = 0; mf < 8; ++mf) {
        int row = wm * 128 + mf * 16 + r;
        int j = row >> 1, c = co + 4 * (row & 1);
        aOff[mf] = (j * 8 + (c ^ (j & 7))) * 16;
    }
    #pragma unroll
    for (int nf = 0; nf < 4; ++nf) {
        int row = wn * 64 + nf * 16 + r;
        int j = row >> 1, c = co + 4 * (row & 1);
        bOff[nf] = 16384 + (j * 8 + (c ^ (j & 7))) * 16;
    }

    f32x4 acc[8][4];
    #pragma unroll
    for (int i = 0; i < 8; ++i)
        #pragma unroll
        for (int j = 0; j < 4; ++j) acc[i][j] = (f32x4){0.f, 0.f, 0.f, 0.f};

    auto GLOAD = [&](int i, int kt) {
        __builtin_amdgcn_global_load_lds(
            (const __attribute__((address_space(1))) unsigned int*)(srcB[i] + kt * 32),
            (__attribute__((address_space(3))) unsigned int*)(lds + ((kt & 3) << 15) + dstOff[i]),
            16, 0, 0);
    };

    // One K-step: 2 phases (mf 0-3, mf 4-7); stage 2 gloads per phase.
    auto STEP = [&](int t, bool stage) {
        const char* base = lds + ((t & 3) << 15);
        short8 fa0[4], fb[4], fa1[4];
        // ---- phase A: stage A-tile of kt+3; read fa0-3, fb0-3; 16 MFMA
        if (stage) { GLOAD(0, t + 3); GLOAD(1, t + 3); }
        #pragma unroll
        for (int f = 0; f < 4; ++f) fa0[f] = *(const short8*)(base + aOff[f]);
        #pragma unroll
        for (int f = 0; f < 4; ++f) fb[f]  = *(const short8*)(base + bOff[f]);
        __builtin_amdgcn_s_barrier();
        LGKM0();
        __builtin_amdgcn_s_setprio(1);
        #pragma unroll
        for (int mf = 0; mf < 4; ++mf)
            #pragma unroll
            for (int nf = 0; nf < 4; ++nf)
                acc[mf][nf] = __builtin_amdgcn_mfma_f32_16x16x32_bf16(
                    fa0[mf], fb[nf], acc[mf][nf], 0, 0, 0);
        __builtin_amdgcn_s_setprio(0);
        __builtin_amdgcn_s_barrier();
        // ---- phase B: stage B-tile of kt+3; read fa4-7; 16 MFMA
        if (stage) { GLOAD(2, t + 3); GLOAD(3, t + 3); }
        #pragma unroll
        for (int f = 0; f < 4; ++f) fa1[f] = *(const short8*)(base + aOff[4 + f]);
        __builtin_amdgcn_s_barrier();
        LGKM0();
        __builtin_amdgcn_s_setprio(1);
        #pragma unroll
        for (int mf = 0; mf < 4; ++mf)
            #pragma unroll
            for (int nf = 0; nf < 4; ++nf)
                acc[4 + mf][nf] = __builtin_amdgcn_mfma_f32_16x16x32_bf16(
                    fa1[mf], fb[nf], acc[4 + mf][nf], 0, 0, 0);
        __builtin_amdgcn_s_setprio(0);
        // caller does WAITVM + barrier
    };

    // Prologue: kt 0,1,2 -> slots 0,1,2 (12 loads); wait oldest 4 (kt0)
    #pragma unroll
    for (int kt = 0; kt < 3; ++kt)
        #pragma unroll
        for (int i = 0; i < 4; ++i) GLOAD(i, kt);
    WAITVM(8);
    __builtin_amdgcn_s_barrier();

    // Steady state: keep 8 loads (kt+2, kt+3) in flight at each barrier
    for (int t = 0; t < 29; ++t) {
        STEP(t, true);
        WAITVM(8);                    // kt=t+1 landed
        __builtin_amdgcn_s_barrier();
    }
    // Tail: kt 29,30,31 already staged
    STEP(29, false);
    WAITVM(4);                        // kt=30 landed
    __builtin_amdgcn_s_barrier();
    STEP(30, false);
    WAITVM(0);                        // kt=31 landed
    __builtin_amdgcn_s_barrier();
    STEP(31, false);

    // Epilogue: C/D layout col = lane&15, row = (lane>>4)*4 + reg  [m89]
    int lr = lane >> 4, lc = lane & 15;
    #pragma unroll
    for (int nf = 0; nf < 4; ++nf) {
        int gc = n0 + wn * 64 + nf * 16 + lc;
        float bv = bias[gc];
        #pragma unroll
        for (int mf = 0; mf < 8; ++mf) {
            int gr = m0 + wm * 128 + mf * 16 + lr * 4;
            f32x4 v = acc[mf][nf];
            #pragma unroll
            for (int j = 0; j < 4; ++j)
                C[(size_t)(gr + j) * NTOK + gc] = v[j] + bv;
        }
    }
}

// ---------------------------------------------------------------------------
extern "C" void kernel_launch(void* const* d_in, const int* in_sizes, int n_in,
                              void* d_out, int out_size, void* d_ws, size_t ws_size,
                              hipStream_t stream)
{
    const int*   raw   = (const int*)  d_in[0];
    const float* enc_w = (const float*)d_in[1];
    const float* fc1   = (const float*)d_in[2];
    const float* fc2   = (const float*)d_in[3];
    const float* dec_w = (const float*)d_in[4];
    const float* dec_b = (const float*)d_in[5];
    const float* mask1 = (const float*)d_in[6];
    const float* mask2 = (const float*)d_in[7];
    float* out = (float*)d_out;

    const int H1 = 512, H2 = 512, NINP = 256, NTOK = 32000;
    const int M = 128 * 32;   // T*B = 4096

    // ws layout (~80MB):
    //   [0,8MB)   st  : state1, then state2 (fp32 [4096][512])
    //   [8,16MB)  spF : s1 fp32; later A2 (s2 dup bf16 [4096][1024])
    //   [16MB,..) W2  : K-interleaved hi/lo bf16 [32000][1024] (65.5MB)
    // maskT scratch lives in d_out (fully overwritten by gemm3).
    char* ws = (char*)d_ws;
    float*          st  = (float*)ws;
    float*          spF = (float*)(ws + (size_t)(8u << 20));
    unsigned int*   a2u = (unsigned int*)(ws + (size_t)(8u << 20));
    unsigned short* A2  = (unsigned short*)(ws + (size_t)(8u << 20));
    unsigned short* W2  = (unsigned short*)(ws + (size_t)(16u << 20));
    float* mT1 = (float*)d_out;            // 128*512 f32 = 256KB
    float* mT2 = (float*)d_out + 65536;    // next 256KB

    // 0. transpose masks into d_out scratch
    maskT_kernel<<<256, 256, 0, stream>>>(mask1, mask2, mT1, mT2);

    // 1. split dec_w -> W2
    int n4 = NTOK * H2 / 4;
    split_kernel<<<(n4 + 255) / 256, 256, 0, stream>>>(dec_w, W2, n4);

    // 2. state1 = gather(enc_w, raw) @ fc1
    gemm_f32_kernel<<<dim3(H1 / 64, M / 64), 256, 0, stream>>>(
        nullptr, fc1, st, M, H1, NINP, raw, enc_w);

    // 3. scan1 -> s1 (fp32)
    scan_kernel<0><<<256, 64, 0, stream>>>(st, mT1, spF, nullptr);

    // 4. state2 = s1 @ fc2
    gemm_f32_kernel<<<dim3(H2 / 64, M / 64), 256, 0, stream>>>(
        spF, fc2, st, M, H2, H1, nullptr, nullptr);

    // 5. scan2 -> s2 duplicated bf16 (overwrites dead s1 region)
    scan_kernel<1><<<256, 64, 0, stream>>>(st, mT2, nullptr, a2u);

    // 6. out = A2 @ W2^T + dec_b (overwrites maskT scratch)
    gemm3_kernel<<<(M / 256) * (NTOK / 256), 512, 0, stream>>>(A2, W2, dec_b, out);

    (void)in_sizes; (void)n_in; (void)out_size; (void)ws_size;
}

// Round 8
// 916.076 us; speedup vs baseline: 1.0526x; 1.0180x over previous
//
#include <hip/hip_runtime.h>

// ---------------------------------------------------------------------------
// RhythmSNN forward, de-sequentialized:
//   0. transpose masks -> maskT[t][h] (scratch inside d_out, dead until gemm3)
//   1. split dec_w (fp32) -> K-interleaved [hi|lo] bf16 W2[32000][1024]   (ws)
//   2. state1 = gather(enc_w, raw) @ fc1          (fp32 128x64 GEMM, fused gather)
//   3. scan1 -> s1 (fp32 {0,1})
//   4. state2 = s1 @ fc2                          (fp32 128x64 GEMM)
//   5. scan2 -> s2 duplicated along K (bf16)      A2[4096][1024]
//   6. out = A2 @ W2^T + dec_b   (MFMA 32x32x16 bf16, ring-4 counted-vmcnt,
//                                 2-phase interleave, conflict-free LDS)
// ---------------------------------------------------------------------------

typedef __attribute__((ext_vector_type(8)))  short short8;
typedef __attribute__((ext_vector_type(16))) float f32x16;
typedef __attribute__((ext_vector_type(8)))  unsigned short us8;

#define WAITVM(N) asm volatile("s_waitcnt vmcnt(" #N ")" ::: "memory")
#define LGKM0()   asm volatile("s_waitcnt lgkmcnt(0)" ::: "memory")

__device__ __forceinline__ unsigned short f2bf(float f) {
    unsigned int u = __float_as_uint(f);
    unsigned int r = (u + 0x7FFFu + ((u >> 16) & 1u)) >> 16;   // RNE
    return (unsigned short)r;
}

// ---------------- 0. mask transpose: maskT[t*512+h] = mask[h*3136+t] -------
__global__ __launch_bounds__(256) void maskT_kernel(
    const float* __restrict__ m1, const float* __restrict__ m2,
    float* __restrict__ t1, float* __restrict__ t2)
{
    int i = blockIdx.x * 256 + threadIdx.x;   // 65536 total
    int h = i >> 7, t = i & 127;
    t1[t * 512 + h] = m1[(size_t)h * 3136 + t];
    t2[t * 512 + h] = m2[(size_t)h * 3136 + t];
}

// ---------------- 1. split dec_w -> K-interleaved hi/lo bf16 ---------------
__global__ __launch_bounds__(256) void split_kernel(
    const float* __restrict__ w, unsigned short* __restrict__ w2, int n4)
{
    int i = blockIdx.x * 256 + threadIdx.x;
    if (i >= n4) return;
    float4 v = ((const float4*)w)[i];
    float vv[4] = {v.x, v.y, v.z, v.w};
    us8 o;
    #pragma unroll
    for (int c = 0; c < 4; ++c) {
        unsigned short hb = f2bf(vv[c]);
        float hf = __uint_as_float(((unsigned int)hb) << 16);
        o[2 * c]     = hb;
        o[2 * c + 1] = f2bf(vv[c] - hf);   // exact residual, then RNE
    }
    ((us8*)w2)[i] = o;
}

// ---------------- 2./4. fp32 GEMM v2: 128x64 tile, 8x4 micro, BK=32 --------
// C[M,N] = A[M,K] @ B[K,N]; gidx gathers A rows from gtable.
// Per-output reduction stays k-ascending fmaf => bit-identical to v1.
// LDS padded (As 132, Bs 68) -> all stage/read patterns <=2-way (free).
__global__ __launch_bounds__(256) void gemm_f32_kernel(
    const float* __restrict__ A, const float* __restrict__ B,
    float* __restrict__ C, int M, int N, int K,
    const int* __restrict__ gidx, const float* __restrict__ gtable)
{
    __shared__ float As[32][132];   // [k][row]
    __shared__ float Bs[32][68];    // [k][n]
    int tid = threadIdx.x;
    int bn0 = blockIdx.x * 64, bm0 = blockIdx.y * 128;
    int ty = tid >> 4, tx = tid & 15;      // 16x16 threads, micro 8x4

    // A staging: thread owns row bm0 + (tid>>1), k-half (tid&1)*16
    int arL  = tid >> 1;
    int akh  = (tid & 1) * 16;
    const float* Abase;
    size_t aoff;
    {
        int grow = bm0 + arL;
        if (gidx) { Abase = gtable; aoff = (size_t)gidx[grow] * K; }
        else      { Abase = A;      aoff = (size_t)grow * K; }
    }

    float acc[8][4];
    #pragma unroll
    for (int i = 0; i < 8; ++i)
        #pragma unroll
        for (int j = 0; j < 4; ++j) acc[i][j] = 0.f;

    for (int k0 = 0; k0 < K; k0 += 32) {
        // load to regs first (no LDS dependence), then double-sync store
        float4 a4[4];
        #pragma unroll
        for (int i = 0; i < 4; ++i)
            a4[i] = *(const float4*)(Abase + aoff + k0 + akh + i * 4);
        float4 b4[2];
        #pragma unroll
        for (int i = 0; i < 2; ++i) {
            int f = tid + 256 * i;
            b4[i] = *(const float4*)(B + (size_t)(k0 + (f >> 4)) * N + bn0 + (f & 15) * 4);
        }
        __syncthreads();   // previous chunk fully consumed
        #pragma unroll
        for (int i = 0; i < 4; ++i) {
            As[akh + i * 4 + 0][arL] = a4[i].x;
            As[akh + i * 4 + 1][arL] = a4[i].y;
            As[akh + i * 4 + 2][arL] = a4[i].z;
            As[akh + i * 4 + 3][arL] = a4[i].w;
        }
        #pragma unroll
        for (int i = 0; i < 2; ++i) {
            int f = tid + 256 * i;
            *(float4*)&Bs[f >> 4][(f & 15) * 4] = b4[i];
        }
        __syncthreads();
        #pragma unroll
        for (int kk = 0; kk < 32; ++kk) {
            float a8[8];
            *(float4*)&a8[0] = *(const float4*)&As[kk][ty * 8];
            *(float4*)&a8[4] = *(const float4*)&As[kk][ty * 8 + 4];
            float4 bq = *(const float4*)&Bs[kk][tx * 4];
            float bb[4] = {bq.x, bq.y, bq.z, bq.w};
            #pragma unroll
            for (int i = 0; i < 8; ++i)
                #pragma unroll
                for (int j = 0; j < 4; ++j) acc[i][j] += a8[i] * bb[j];
        }
    }
    #pragma unroll
    for (int i = 0; i < 8; ++i) {
        float4 v = {acc[i][0], acc[i][1], acc[i][2], acc[i][3]};
        *(float4*)(C + (size_t)(bm0 + ty * 8 + i) * N + bn0 + tx * 4) = v;
    }
}

// ---------------- 3./5. membrane scan (batched loads, coalesced) -----------
template <int DUP>
__global__ __launch_bounds__(64) void scan_kernel(
    const float* __restrict__ state, const float* __restrict__ maskT,
    float* __restrict__ outF, unsigned int* __restrict__ outU)
{
    int tid = blockIdx.x * 64 + threadIdx.x;   // < 32*512
    int b = tid >> 9, h = tid & 511;
    float mem = 0.f;
    for (int t0 = 0; t0 < 128; t0 += 8) {
        float st8[8], m8[8];
        #pragma unroll
        for (int u = 0; u < 8; ++u) {
            st8[u] = state[(size_t)((t0 + u) * 32 + b) * 512 + h];
            m8[u]  = maskT[(t0 + u) * 512 + h];
        }
        #pragma unroll
        for (int u = 0; u < 8; ++u) {
            float nm = (mem > 0.6f) ? st8[u] : mem * 0.6f + st8[u];  // old-mem reset
            mem = (m8[u] == 0.0f) ? mem : nm;
            float spf = (mem > 0.6f) ? m8[u] : 0.0f;                 // heaviside*mask
            size_t ridx = (size_t)((t0 + u) * 32 + b) * 512 + h;
            if (DUP) outU[ridx] = f2bf(spf) * 0x10001u;              // dup along K
            else     outF[ridx] = spf;
        }
    }
}

// ---------------- 6. decode GEMM: 32x32x16 MFMA, ring-4 + 2-phase ----------
// C[4096, 32000] = A[4096,1024] @ W[32000,1024]^T + bias
// 512 thr = 8 waves (2M x 4N), wave tile 128x64 = 4x2 of 32x32 frags.
// BK=32 slots, ring-4 (128 KB), stage kt=t+3, WAITVM(8) counted (never 0
// until tail). Paired-row LDS (row j = tile rows {2j,2j+1}, 8x16B chunks,
// c ^= j&7): measured 0 conflicts in round 6; 32x32 frag reads audited
// 2-way per 16-lane phase (free). Per step 2 phases {2 gloads + 6 ds_reads,
// bar, lgkm0, prio1 8 MFMA prio0}; end-of-step WAITVM(8) + bar.
__global__ __launch_bounds__(512, 2) void gemm3_kernel(
    const unsigned short* __restrict__ A,
    const unsigned short* __restrict__ W,
    const float* __restrict__ bias, float* __restrict__ C)
{
    constexpr int K = 1024, NTOK = 32000;
    __shared__ char lds[131072];

    int tid  = threadIdx.x;
    int lane = tid & 63;
    int wid  = __builtin_amdgcn_readfirstlane(tid >> 6);

    // XCD bijective swizzle: 2000 blocks, 250/XCD; mt fast -> W-panel L2 reuse
    int bid = blockIdx.x;
    int swz = (bid & 7) * 250 + (bid >> 3);
    int mt = swz & 15;          // 16 M-tiles
    int nt = swz >> 4;          // 125 N-tiles
    int m0 = mt * 256, n0 = nt * 256;

    int wm = wid >> 2, wn = wid & 3;   // wave rows wm*128+, cols wn*64+

    // Stage sources (byte-identical to round-6 verified mapping):
    // LDS chunk (j, cp) <- global (row = 2j + (c>>2), koct = c&3), c = cp^(j&7)
    const unsigned short* srcB[4];
    int dstOff[4];
    #pragma unroll
    for (int i = 0; i < 4; ++i) {
        int q   = i * 512 + tid;
        int isB = q >> 10;
        int qq  = q & 1023;
        int j   = qq >> 3;
        int cp  = qq & 7;
        int c   = cp ^ (j & 7);
        int row = 2 * j + (c >> 2);
        srcB[i] = (isB ? W + (size_t)(n0 + row) * K
                       : A + (size_t)(m0 + row) * K) + (c & 3) * 8;
        dstOff[i] = (i * 512 + wid * 64) * 16;  // wave-uniform; HW adds lane*16
    }

    // 32x32 frag read offsets (ki=0); ki=1 applies ^32 (c has bit1 clear, so
    // c^2 == c+2 and XOR commutes with the j&7 swizzle).
    // A operand layout: row = lane&31, k = (lane>>5)*8 + e (analog of the
    // verified 16x16x32 mapping). chunk c = (lane>>5) + 2*ki + 4*(R&1).
    int cl = lane & 31, hi5 = lane >> 5;
    int aOff[4], bOff[2];
    #pragma unroll
    for (int mi = 0; mi < 4; ++mi) {
        int R = wm * 128 + mi * 32 + cl;
        int j = R >> 1;
        int c = (hi5 + 4 * (R & 1)) ^ (j & 7);
        aOff[mi] = j * 128 + c * 16;
    }
    #pragma unroll
    for (int ni = 0; ni < 2; ++ni) {
        int R = wn * 64 + ni * 32 + cl;
        int j = R >> 1;
        int c = (hi5 + 4 * (R & 1)) ^ (j & 7);
        bOff[ni] = 16384 + j * 128 + c * 16;
    }

    f32x16 acc[4][2];
    #pragma unroll
    for (int i = 0; i < 4; ++i)
        #pragma unroll
        for (int j = 0; j < 2; ++j)
            #pragma unroll
            for (int e = 0; e < 16; ++e) acc[i][j][e] = 0.f;

    auto GLOAD = [&](int i, int kt) {
        __builtin_amdgcn_global_load_lds(
            (const __attribute__((address_space(1))) unsigned int*)(srcB[i] + kt * 32),
            (__attribute__((address_space(3))) unsigned int*)(lds + ((kt & 3) << 15) + dstOff[i]),
            16, 0, 0);
    };

    // One K-step: 2 phases (ki=0: stage A-tile of kt+3; ki=1: stage B-tile)
    auto STEP = [&](int t, bool stage) {
        const char* base = lds + ((t & 3) << 15);
        #pragma unroll
        for (int ki = 0; ki < 2; ++ki) {
            if (stage) { GLOAD(2 * ki, t + 3); GLOAD(2 * ki + 1, t + 3); }
            short8 fa[4], fb[2];
            int kx = ki * 32;   // byte-offset XOR for ki
            #pragma unroll
            for (int mi = 0; mi < 4; ++mi)
                fa[mi] = *(const short8*)(base + (aOff[mi] ^ kx));
            #pragma unroll
            for (int ni = 0; ni < 2; ++ni)
                fb[ni] = *(const short8*)(base + (bOff[ni] ^ kx));
            __builtin_amdgcn_s_barrier();
            LGKM0();
            __builtin_amdgcn_sched_barrier(0);
            __builtin_amdgcn_s_setprio(1);
            #pragma unroll
            for (int mi = 0; mi < 4; ++mi)
                #pragma unroll
                for (int ni = 0; ni < 2; ++ni)
                    acc[mi][ni] = __builtin_amdgcn_mfma_f32_32x32x16_bf16(
                        fa[mi], fb[ni], acc[mi][ni], 0, 0, 0);
            __builtin_amdgcn_s_setprio(0);
        }
        // caller does WAITVM + barrier
    };

    // Prologue: kt 0,1,2 -> slots 0,1,2 (12 loads); wait oldest 4 (kt0)
    #pragma unroll
    for (int kt = 0; kt < 3; ++kt)
        #pragma unroll
        for (int i = 0; i < 4; ++i) GLOAD(i, kt);
    WAITVM(8);
    __builtin_amdgcn_s_barrier();

    // Steady state: keep 8 loads (kt+2, kt+3) in flight at each barrier
    for (int t = 0; t < 29; ++t) {
        STEP(t, true);
        WAITVM(8);                    // kt=t+1 landed
        __builtin_amdgcn_s_barrier();
    }
    STEP(29, false);
    WAITVM(4);                        // kt=30 landed
    __builtin_amdgcn_s_barrier();
    STEP(30, false);
    WAITVM(0);                        // kt=31 landed
    __builtin_amdgcn_s_barrier();
    STEP(31, false);

    // Epilogue: 32x32 C/D layout: col = lane&31, row = (reg&3)+8*(reg>>2)+4*hi5
    #pragma unroll
    for (int ni = 0; ni < 2; ++ni) {
        int gc = n0 + wn * 64 + ni * 32 + cl;
        float bv = bias[gc];
        #pragma unroll
        for (int mi = 0; mi < 4; ++mi) {
            f32x16 v = acc[mi][ni];
            #pragma unroll
            for (int reg = 0; reg < 16; ++reg) {
                int gr = m0 + wm * 128 + mi * 32 + (reg & 3) + 8 * (reg >> 2) + 4 * hi5;
                C[(size_t)gr * NTOK + gc] = v[reg] + bv;
            }
        }
    }
}

// ---------------------------------------------------------------------------
extern "C" void kernel_launch(void* const* d_in, const int* in_sizes, int n_in,
                              void* d_out, int out_size, void* d_ws, size_t ws_size,
                              hipStream_t stream)
{
    const int*   raw   = (const int*)  d_in[0];
    const float* enc_w = (const float*)d_in[1];
    const float* fc1   = (const float*)d_in[2];
    const float* fc2   = (const float*)d_in[3];
    const float* dec_w = (const float*)d_in[4];
    const float* dec_b = (const float*)d_in[5];
    const float* mask1 = (const float*)d_in[6];
    const float* mask2 = (const float*)d_in[7];
    float* out = (float*)d_out;

    const int H1 = 512, H2 = 512, NINP = 256, NTOK = 32000;
    const int M = 128 * 32;   // T*B = 4096

    // ws layout (~80MB):
    //   [0,8MB)   st  : state1, then state2 (fp32 [4096][512])
    //   [8,16MB)  spF : s1 fp32; later A2 (s2 dup bf16 [4096][1024])
    //   [16MB,..) W2  : K-interleaved hi/lo bf16 [32000][1024] (65.5MB)
    // maskT scratch lives in d_out (fully overwritten by gemm3).
    char* ws = (char*)d_ws;
    float*          st  = (float*)ws;
    float*          spF = (float*)(ws + (size_t)(8u << 20));
    unsigned int*   a2u = (unsigned int*)(ws + (size_t)(8u << 20));
    unsigned short* A2  = (unsigned short*)(ws + (size_t)(8u << 20));
    unsigned short* W2  = (unsigned short*)(ws + (size_t)(16u << 20));
    float* mT1 = (float*)d_out;            // 128*512 f32 = 256KB
    float* mT2 = (float*)d_out + 65536;    // next 256KB

    // 0. transpose masks into d_out scratch
    maskT_kernel<<<256, 256, 0, stream>>>(mask1, mask2, mT1, mT2);

    // 1. split dec_w -> W2
    int n4 = NTOK * H2 / 4;
    split_kernel<<<(n4 + 255) / 256, 256, 0, stream>>>(dec_w, W2, n4);

    // 2. state1 = gather(enc_w, raw) @ fc1
    gemm_f32_kernel<<<dim3(H1 / 64, M / 128), 256, 0, stream>>>(
        nullptr, fc1, st, M, H1, NINP, raw, enc_w);

    // 3. scan1 -> s1 (fp32)
    scan_kernel<0><<<256, 64, 0, stream>>>(st, mT1, spF, nullptr);

    // 4. state2 = s1 @ fc2
    gemm_f32_kernel<<<dim3(H2 / 64, M / 128), 256, 0, stream>>>(
        spF, fc2, st, M, H2, H1, nullptr, nullptr);

    // 5. scan2 -> s2 duplicated bf16 (overwrites dead s1 region)
    scan_kernel<1><<<256, 64, 0, stream>>>(st, mT2, nullptr, a2u);

    // 6. out = A2 @ W2^T + dec_b (overwrites maskT scratch)
    gemm3_kernel<<<(M / 256) * (NTOK / 256), 512, 0, stream>>>(A2, W2, dec_b, out);

    (void)in_sizes; (void)n_in; (void)out_size; (void)ws_size;
}